// Round 14
// baseline (371.531 us; speedup 1.0000x reference)
//
#include <hip/hip_runtime.h>
#include <hip/hip_bf16.h>
#include <math.h>
#include <stdint.h>

#define N_NODES 50000
#define N_EDGES 800000
#define N_GRAPHS 256
#define F_IN 64
#define F_HID 128
#define N_HID 512
#define N_OUT 256

#define SCAN_B 256
#define SCAN_NBLK ((N_NODES + SCAN_B - 1) / SCAN_B)   // 196

// pack two fp32 into a uint holding two bf16 (RNE); low16 = a, high16 = b
__device__ __forceinline__ unsigned int bf16pair(float a, float b) {
    unsigned int ua = __float_as_uint(a);
    unsigned int ub = __float_as_uint(b);
    ua += 0x7fffu + ((ua >> 16) & 1u);
    ub += 0x7fffu + ((ub >> 16) & 1u);
    return (ua >> 16) | (ub & 0xffff0000u);
}
__device__ __forceinline__ float bf16lo(unsigned int u) { return __uint_as_float(u << 16); }
__device__ __forceinline__ float bf16hi(unsigned int u) { return __uint_as_float(u & 0xffff0000u); }

// ---------------------------------------------------------------------------
// K0: xb'[s] = bf16(dis[s] * x[s])  (pre-scaled gather table; runs after scan)
__global__ void cvt_bf16(const float* __restrict__ in, const float* __restrict__ dis,
                         unsigned int* __restrict__ out, int n4) {
    int idx = blockIdx.x * blockDim.x + threadIdx.x;
    if (idx < n4) {
        int node = idx >> 4;                  // 16 float4 per 64-f row
        float d = dis[node];
        float4 v = ((const float4*)in)[idx];
        ((uint2*)out)[idx] = make_uint2(bf16pair(d * v.x, d * v.y),
                                        bf16pair(d * v.z, d * v.w));
    }
}

// ---------------------------------------------------------------------------
// K1: in-degree count (edges only; self-loop added analytically later)
__global__ void count_deg(const int* __restrict__ ei, int* __restrict__ indeg) {
    int e = blockIdx.x * blockDim.x + threadIdx.x;
    if (e < N_EDGES) atomicAdd(&indeg[ei[N_EDGES + e]], 1);
}

// ---------------------------------------------------------------------------
// K2a: per-block reduction of indeg chunks -> blockSums
__global__ __launch_bounds__(SCAN_B) void scan_partial(const int* __restrict__ indeg,
                                                       int* __restrict__ blockSums) {
    __shared__ int sdata[SCAN_B];
    int i = blockIdx.x * SCAN_B + threadIdx.x;
    sdata[threadIdx.x] = (i < N_NODES) ? indeg[i] : 0;
    __syncthreads();
    for (int off = SCAN_B / 2; off > 0; off >>= 1) {
        if (threadIdx.x < off) sdata[threadIdx.x] += sdata[threadIdx.x + off];
        __syncthreads();
    }
    if (threadIdx.x == 0) blockSums[blockIdx.x] = sdata[0];
}

// K2b: single tiny block: exclusive scan of blockSums (SCAN_NBLK <= 256)
__global__ __launch_bounds__(SCAN_B) void scan_block_sums(int* __restrict__ blockSums) {
    __shared__ int buf[SCAN_B];
    int tid = threadIdx.x;
    int v = (tid < SCAN_NBLK) ? blockSums[tid] : 0;
    buf[tid] = v;
    __syncthreads();
    for (int off = 1; off < SCAN_B; off <<= 1) {
        int t = (tid >= off) ? buf[tid - off] : 0;
        __syncthreads();
        buf[tid] += t;
        __syncthreads();
    }
    if (tid < SCAN_NBLK) blockSums[tid] = buf[tid] - v;   // exclusive
}

// K2c: per-block exclusive scan + block offset -> offsets; also dis = rsqrt(deg+1)
__global__ __launch_bounds__(SCAN_B) void scan_final(const int* __restrict__ indeg,
                                                     const int* __restrict__ blockSums,
                                                     int* __restrict__ offsets,
                                                     float* __restrict__ dis) {
    __shared__ int buf[SCAN_B];
    int tid = threadIdx.x;
    int i = blockIdx.x * SCAN_B + tid;
    int v = (i < N_NODES) ? indeg[i] : 0;
    if (i < N_NODES) dis[i] = rsqrtf((float)(v + 1));
    buf[tid] = v;
    __syncthreads();
    for (int off = 1; off < SCAN_B; off <<= 1) {
        int t = (tid >= off) ? buf[tid - off] : 0;
        __syncthreads();
        buf[tid] += t;
        __syncthreads();
    }
    if (i < N_NODES) offsets[i] = blockSums[blockIdx.x] + buf[tid] - v;
    if (i == 0) offsets[N_NODES] = N_EDGES;   // total is statically known
}

// ---------------------------------------------------------------------------
// K3: scatter edges into CSR (by dst). Entry = ushort src (weights folded
// into the pre-scaled tables) -> 2 B/edge.
__global__ void build_csr(const int* __restrict__ ei, const int* __restrict__ offsets,
                          int* __restrict__ cursor, unsigned short* __restrict__ csr) {
    int e = blockIdx.x * blockDim.x + threadIdx.x;
    if (e < N_EDGES) {
        int s = ei[e];
        int d = ei[N_EDGES + e];
        int pos = atomicAdd(&cursor[d], 1);
        csr[offsets[d] + pos] = (unsigned short)s;
    }
}

// ---------------------------------------------------------------------------
// K4: C[M, col0..col0+64) = A[M,K] @ W[K,128] tile. 64x64 tile, 128 threads,
// 8x4/thread, grid (782, 2). BF16OUT: epilogue packs dis[r]-pre-scaled bf16.
template <int K, bool BIASRELU, bool BF16OUT>
__global__ __launch_bounds__(128) void gemm64(const float* __restrict__ A,
                                              const float* __restrict__ W,
                                              const float* __restrict__ bias,
                                              const float* __restrict__ disv,
                                              void* __restrict__ outp, int M) {
    const int BM = 64, BN = 64, KC = 32, LDA = 36;
    __shared__ float As[BM * LDA];     // 9.2 KB
    __shared__ float Bs[KC * BN];      // 8 KB
    int tid = threadIdx.x;
    int tx = tid & 15;                 // cols col0 + tx*4
    int ty = tid >> 4;                 // 0..7; rows ty + 8*i
    int row0 = blockIdx.x * BM;
    int col0 = blockIdx.y * BN;
    float acc[8][4] = {};
    for (int k0 = 0; k0 < K; k0 += KC) {
#pragma unroll
        for (int u = 0; u < 4; ++u) {
            int f4id = tid + 128 * u;
            int m = f4id >> 3;                 // 0..63
            int ks = (f4id & 7) * 4;           // 0,4,..28
            int r = row0 + m;
            float4 v = make_float4(0.f, 0.f, 0.f, 0.f);
            if (r < M) v = *(const float4*)&A[(size_t)r * K + k0 + ks];
            *(float4*)&As[m * LDA + ks] = v;
        }
#pragma unroll
        for (int u = 0; u < 4; ++u) {
            int f4id = tid + 128 * u;
            int kk = f4id >> 4;                // 0..31
            int n4 = (f4id & 15) * 4;          // 0..60
            *(float4*)&Bs[kk * BN + n4] =
                *(const float4*)&W[(size_t)(k0 + kk) * 128 + col0 + n4];
        }
        __syncthreads();
#pragma unroll
        for (int kc = 0; kc < KC; kc += 4) {
            float4 av[8], bv[4];
#pragma unroll
            for (int i = 0; i < 8; ++i)
                av[i] = *(const float4*)&As[(ty + 8 * i) * LDA + kc];
#pragma unroll
            for (int q = 0; q < 4; ++q)
                bv[q] = *(const float4*)&Bs[(kc + q) * BN + tx * 4];
#pragma unroll
            for (int q = 0; q < 4; ++q) {
#pragma unroll
                for (int i = 0; i < 8; ++i) {
                    float a = ((const float*)&av[i])[q];
                    acc[i][0] += a * bv[q].x;  acc[i][1] += a * bv[q].y;
                    acc[i][2] += a * bv[q].z;  acc[i][3] += a * bv[q].w;
                }
            }
        }
        __syncthreads();
    }
    int c0 = col0 + tx * 4;
#pragma unroll
    for (int i = 0; i < 8; ++i) {
        int r = row0 + ty + 8 * i;
        if (r < M) {
            float4 v0 = make_float4(acc[i][0], acc[i][1], acc[i][2], acc[i][3]);
            if (BIASRELU) {
                v0.x = fmaxf(v0.x + bias[c0], 0.f);   v0.y = fmaxf(v0.y + bias[c0+1], 0.f);
                v0.z = fmaxf(v0.z + bias[c0+2], 0.f); v0.w = fmaxf(v0.w + bias[c0+3], 0.f);
            }
            if (BF16OUT) {
                float dr = disv[r];
                uint2 o = make_uint2(bf16pair(dr * v0.x, dr * v0.y),
                                     bf16pair(dr * v0.z, dr * v0.w));
                ((uint2*)outp)[((size_t)r * 128 + c0) >> 2] = o;
            } else {
                *(float4*)&((float*)outp)[(size_t)r * 128 + c0] = v0;
            }
        }
    }
}

// ---------------------------------------------------------------------------
// K5a: F=128 aggregate over PRE-SCALED bf16 table (hb'[s] = dis[s]*h[s]).
// uint4 lanes: 16 lanes cover a 256B row -> FOUR edges per gather inst,
// 32 edges in flight per 8 insts. xor-16 + xor-32 combine. fp32 accumulate.
template <bool RELU, bool BIAS, bool BF16OUT>
__global__ __launch_bounds__(256) void aggregate128b(const uint4* __restrict__ hb4,
                                                     const int* __restrict__ offsets,
                                                     const unsigned short* __restrict__ csr,
                                                     const float* __restrict__ dis,
                                                     const float* __restrict__ bias,
                                                     void* __restrict__ outp) {
    int wave = threadIdx.x >> 6;
    int lane = threadIdx.x & 63;
    int i = blockIdx.x * 4 + wave;
    if (i >= N_NODES) return;
    int sub = lane >> 4;              // 0..3: which edge of the quad
    int q   = lane & 15;              // uint4 index within the 16-uint4 row
    float a0 = 0.f, a1 = 0.f, a2 = 0.f, a3 = 0.f;
    float a4 = 0.f, a5 = 0.f, a6 = 0.f, a7 = 0.f;
    int j = offsets[i], s1 = offsets[i + 1];
    for (; j < s1; j += 32) {
        int s[8]; float m[8];
#pragma unroll
        for (int u = 0; u < 8; ++u) {
            int e = j + 4 * u + sub;
            bool valid = e < s1;
            s[u] = valid ? (int)csr[e] : 0;
            m[u] = valid ? 1.f : 0.f;
        }
        uint4 r[8];
#pragma unroll
        for (int u = 0; u < 8; ++u) r[u] = hb4[(size_t)s[u] * 16 + q];
#pragma unroll
        for (int u = 0; u < 8; ++u) {
            a0 += m[u] * bf16lo(r[u].x);  a1 += m[u] * bf16hi(r[u].x);
            a2 += m[u] * bf16lo(r[u].y);  a3 += m[u] * bf16hi(r[u].y);
            a4 += m[u] * bf16lo(r[u].z);  a5 += m[u] * bf16hi(r[u].z);
            a6 += m[u] * bf16lo(r[u].w);  a7 += m[u] * bf16hi(r[u].w);
        }
    }
    a0 += __shfl_xor(a0, 16, 64);  a1 += __shfl_xor(a1, 16, 64);
    a2 += __shfl_xor(a2, 16, 64);  a3 += __shfl_xor(a3, 16, 64);
    a4 += __shfl_xor(a4, 16, 64);  a5 += __shfl_xor(a5, 16, 64);
    a6 += __shfl_xor(a6, 16, 64);  a7 += __shfl_xor(a7, 16, 64);
    a0 += __shfl_xor(a0, 32, 64);  a1 += __shfl_xor(a1, 32, 64);
    a2 += __shfl_xor(a2, 32, 64);  a3 += __shfl_xor(a3, 32, 64);
    a4 += __shfl_xor(a4, 32, 64);  a5 += __shfl_xor(a5, 32, 64);
    a6 += __shfl_xor(a6, 32, 64);  a7 += __shfl_xor(a7, 32, 64);
    uint4 su = hb4[(size_t)i * 16 + q];     // self: weight 1 in scaled domain
    a0 += bf16lo(su.x);  a1 += bf16hi(su.x);
    a2 += bf16lo(su.y);  a3 += bf16hi(su.y);
    a4 += bf16lo(su.z);  a5 += bf16hi(su.z);
    a6 += bf16lo(su.w);  a7 += bf16hi(su.w);
    float dii = dis[i];
    a0 *= dii; a1 *= dii; a2 *= dii; a3 *= dii;
    a4 *= dii; a5 *= dii; a6 *= dii; a7 *= dii;
    if (BIAS) {
        float4 b0v = ((const float4*)bias)[2 * q];       // features 8q..8q+3
        float4 b1v = ((const float4*)bias)[2 * q + 1];   // features 8q+4..8q+7
        a0 += b0v.x; a1 += b0v.y; a2 += b0v.z; a3 += b0v.w;
        a4 += b1v.x; a5 += b1v.y; a6 += b1v.z; a7 += b1v.w;
    }
    if (RELU) {
        a0 = fmaxf(a0, 0.f); a1 = fmaxf(a1, 0.f); a2 = fmaxf(a2, 0.f); a3 = fmaxf(a3, 0.f);
        a4 = fmaxf(a4, 0.f); a5 = fmaxf(a5, 0.f); a6 = fmaxf(a6, 0.f); a7 = fmaxf(a7, 0.f);
    }
    if (sub == 0) {
        if (BF16OUT) {  // next gather table: pre-scale by dis[i]
            uint4 o;
            o.x = bf16pair(dii * a0, dii * a1);
            o.y = bf16pair(dii * a2, dii * a3);
            o.z = bf16pair(dii * a4, dii * a5);
            o.w = bf16pair(dii * a6, dii * a7);
            ((uint4*)outp)[(size_t)i * 16 + q] = o;
        } else {
            ((float4*)outp)[(size_t)i * 32 + 2 * q]     = make_float4(a0, a1, a2, a3);
            ((float4*)outp)[(size_t)i * 32 + 2 * q + 1] = make_float4(a4, a5, a6, a7);
        }
    }
}

// K5b: F=64 aggregate over pre-scaled bf16 x-table. uint4 lanes: 8 lanes per
// 128B row -> EIGHT edges per gather inst. xor-8/16/32 combine; self from fp32 x.
__global__ __launch_bounds__(256) void aggregate_xb(const uint4* __restrict__ xb4,
                                                    const float* __restrict__ x,
                                                    const int* __restrict__ offsets,
                                                    const unsigned short* __restrict__ csr,
                                                    const float* __restrict__ dis,
                                                    float* __restrict__ out) {
    int wave = threadIdx.x >> 6;
    int lane = threadIdx.x & 63;
    int i = blockIdx.x * 4 + wave;
    if (i >= N_NODES) return;
    int sub = lane >> 3;              // 0..7: which edge of the octet
    int q   = lane & 7;               // uint4 index within the 8-uint4 row
    float a0 = 0.f, a1 = 0.f, a2 = 0.f, a3 = 0.f;
    float a4 = 0.f, a5 = 0.f, a6 = 0.f, a7 = 0.f;
    int j = offsets[i], s1 = offsets[i + 1];
    for (; j < s1; j += 64) {
        int s[8]; float m[8];
#pragma unroll
        for (int u = 0; u < 8; ++u) {
            int e = j + 8 * u + sub;
            bool valid = e < s1;
            s[u] = valid ? (int)csr[e] : 0;
            m[u] = valid ? 1.f : 0.f;
        }
        uint4 r[8];
#pragma unroll
        for (int u = 0; u < 8; ++u) r[u] = xb4[(size_t)s[u] * 8 + q];
#pragma unroll
        for (int u = 0; u < 8; ++u) {
            a0 += m[u] * bf16lo(r[u].x);  a1 += m[u] * bf16hi(r[u].x);
            a2 += m[u] * bf16lo(r[u].y);  a3 += m[u] * bf16hi(r[u].y);
            a4 += m[u] * bf16lo(r[u].z);  a5 += m[u] * bf16hi(r[u].z);
            a6 += m[u] * bf16lo(r[u].w);  a7 += m[u] * bf16hi(r[u].w);
        }
    }
#pragma unroll
    for (int d = 8; d <= 32; d <<= 1) {
        a0 += __shfl_xor(a0, d, 64);  a1 += __shfl_xor(a1, d, 64);
        a2 += __shfl_xor(a2, d, 64);  a3 += __shfl_xor(a3, d, 64);
        a4 += __shfl_xor(a4, d, 64);  a5 += __shfl_xor(a5, d, 64);
        a6 += __shfl_xor(a6, d, 64);  a7 += __shfl_xor(a7, d, 64);
    }
    float dii = dis[i];
    float d2 = dii * dii;
    float4 sx0 = ((const float4*)x)[(size_t)i * 16 + 2 * q];
    float4 sx1 = ((const float4*)x)[(size_t)i * 16 + 2 * q + 1];
    a0 = dii * a0 + d2 * sx0.x;  a1 = dii * a1 + d2 * sx0.y;
    a2 = dii * a2 + d2 * sx0.z;  a3 = dii * a3 + d2 * sx0.w;
    a4 = dii * a4 + d2 * sx1.x;  a5 = dii * a5 + d2 * sx1.y;
    a6 = dii * a6 + d2 * sx1.z;  a7 = dii * a7 + d2 * sx1.w;
    if (sub == 0) {
        ((float4*)out)[(size_t)i * 16 + 2 * q]     = make_float4(a0, a1, a2, a3);
        ((float4*)out)[(size_t)i * 16 + 2 * q + 1] = make_float4(a4, a5, a6, a7);
    }
}

// ---------------------------------------------------------------------------
// K6: mean-pool (batch is sorted -> register-accumulate 16 nodes, flush on change)
__global__ __launch_bounds__(128) void pool16(const float* __restrict__ h,
                                              const int* __restrict__ batch,
                                              float* __restrict__ g_acc,
                                              float* __restrict__ g_cnt) {
    const int NB = 16;
    int base = blockIdx.x * NB;
    int f = threadIdx.x;
    float acc = 0.f;
    int cur = -1, cnt = 0;
    for (int n = 0; n < NB; ++n) {
        int i = base + n;
        if (i >= N_NODES) break;
        int b = batch[i];
        if (b != cur) {
            if (cur >= 0) {
                atomicAdd(&g_acc[(size_t)cur * F_HID + f], acc);
                if (f == 0) atomicAdd(&g_cnt[cur], (float)cnt);
            }
            cur = b; acc = 0.f; cnt = 0;
        }
        acc += h[(size_t)i * F_HID + f];
        cnt++;
    }
    if (cur >= 0) {
        atomicAdd(&g_acc[(size_t)cur * F_HID + f], acc);
        if (f == 0) atomicAdd(&g_cnt[cur], (float)cnt);
    }
}

// ---------------------------------------------------------------------------
// K6b: g2 = (g_acc/cnt) @ W2 + b2   [256,128]@[128,128]  (layer-2 linear,
// commuted past aggregate+pool: pool(Â(hW2)+b2) == pool(Âh)W2 + b2)
__global__ __launch_bounds__(128) void graph_w2(const float* __restrict__ g_acc,
                                                const float* __restrict__ g_cnt,
                                                const float* __restrict__ W2,
                                                const float* __restrict__ b2,
                                                float* __restrict__ g2) {
    __shared__ float row[F_HID];
    int g = blockIdx.x;
    int t = threadIdx.x;              // 0..127
    float c = g_cnt[g];
    row[t] = g_acc[(size_t)g * F_HID + t] / fmaxf(c, 1.0f);
    __syncthreads();
    float acc = b2[t];
    for (int k = 0; k < F_HID; ++k) acc += row[k] * W2[(size_t)k * F_HID + t];
    g2[(size_t)g * F_HID + t] = acc;
}

// K7: g_hid = relu(g2 @ Wm1 + bm1)   [256,128]@[128,512]
__global__ __launch_bounds__(512) void mlp1(const float* __restrict__ g2,
                                            const float* __restrict__ Wm1,
                                            const float* __restrict__ bm1,
                                            float* __restrict__ g_hid) {
    __shared__ float row[F_HID];
    int g = blockIdx.x;
    int t = threadIdx.x;              // 0..511
    if (t < F_HID) row[t] = g2[(size_t)g * F_HID + t];
    __syncthreads();
    float acc = bm1[t];
    for (int k = 0; k < F_HID; ++k) acc += row[k] * Wm1[(size_t)k * N_HID + t];
    g_hid[(size_t)g * N_HID + t] = fmaxf(acc, 0.f);
}

// K8: out = g_hid @ Wm2 + bm2   [256,512]@[512,256]
__global__ __launch_bounds__(256) void mlp2(const float* __restrict__ g_hid,
                                            const float* __restrict__ Wm2,
                                            const float* __restrict__ bm2,
                                            float* __restrict__ out) {
    __shared__ float row[N_HID];
    int g = blockIdx.x;
    int t = threadIdx.x;              // 0..255
    row[t] = g_hid[(size_t)g * N_HID + t];
    row[t + 256] = g_hid[(size_t)g * N_HID + t + 256];
    __syncthreads();
    float acc = bm2[t];
    for (int k = 0; k < N_HID; ++k) acc += row[k] * Wm2[(size_t)k * N_OUT + t];
    out[(size_t)g * N_OUT + t] = acc;
}

// ---------------------------------------------------------------------------
extern "C" void kernel_launch(void* const* d_in, const int* in_sizes, int n_in,
                              void* d_out, int out_size, void* d_ws, size_t ws_size,
                              hipStream_t stream) {
    const float* x   = (const float*)d_in[0];
    const int* ei    = (const int*)d_in[1];     // [2, E] int32
    const int* batch = (const int*)d_in[2];
    const float* W0 = (const float*)d_in[3];  const float* b0 = (const float*)d_in[4];
    const float* W1 = (const float*)d_in[5];  const float* b1 = (const float*)d_in[6];
    const float* W2 = (const float*)d_in[7];  const float* b2 = (const float*)d_in[8];
    const float* Wm1 = (const float*)d_in[9];  const float* bm1 = (const float*)d_in[10];
    const float* Wm2 = (const float*)d_in[11]; const float* bm2 = (const float*)d_in[12];

    // bump allocator on d_ws, 256B-aligned slots
    char* p = (char*)d_ws;
    auto alloc = [&](size_t bytes) -> char* {
        char* r = p;
        p += (bytes + 255) & ~(size_t)255;
        return r;
    };
    // zero-init region (contiguous in allocation order)
    int*   indeg  = (int*)alloc(N_NODES * 4);
    int*   cursor = (int*)alloc(N_NODES * 4);
    float* g_acc  = (float*)alloc((size_t)N_GRAPHS * F_HID * 4);
    float* g_cnt  = (float*)alloc(N_GRAPHS * 4);
    size_t zero_bytes = (size_t)(p - (char*)indeg);
    // rest
    int*   blockSums = (int*)alloc(SCAN_NBLK * 4);
    int*   offsets = (int*)alloc((N_NODES + 1) * 4);
    float* dis     = (float*)alloc(N_NODES * 4);
    unsigned short* csr = (unsigned short*)alloc((size_t)N_EDGES * 2);
    unsigned int* xb     = (unsigned int*)alloc((size_t)N_NODES * F_IN / 2 * 4);   // bf16 x'
    float*        ax     = (float*)alloc((size_t)N_NODES * F_IN * 4);
    float*        h_a    = (float*)alloc((size_t)N_NODES * F_HID * 4);
    unsigned int* h_tmpb = (unsigned int*)alloc((size_t)N_NODES * F_HID / 2 * 4);  // bf16'
    unsigned int* h_bb   = (unsigned int*)alloc((size_t)N_NODES * F_HID / 2 * 4);  // bf16'
    float*        agg2   = (float*)alloc((size_t)N_NODES * F_HID * 4);
    float*        g2     = (float*)alloc((size_t)N_GRAPHS * F_HID * 4);
    float*        g_hid  = (float*)alloc((size_t)N_GRAPHS * N_HID * 4);
    (void)ws_size; (void)in_sizes; (void)n_in; (void)out_size;

    (void)hipMemsetAsync(indeg, 0, zero_bytes, stream);

    count_deg<<<(N_EDGES + 255) / 256, 256, 0, stream>>>(ei, indeg);
    scan_partial<<<SCAN_NBLK, SCAN_B, 0, stream>>>(indeg, blockSums);
    scan_block_sums<<<1, SCAN_B, 0, stream>>>(blockSums);
    scan_final<<<SCAN_NBLK, SCAN_B, 0, stream>>>(indeg, blockSums, offsets, dis);
    build_csr<<<(N_EDGES + 255) / 256, 256, 0, stream>>>(ei, offsets, cursor, csr);
    cvt_bf16<<<(N_NODES * F_IN / 4 + 255) / 256, 256, 0, stream>>>(x, dis, xb, N_NODES * F_IN / 4);

    int agg_grid = (N_NODES + 3) / 4;          // 4 nodes (waves) per block
    dim3 gemm_grid((N_NODES + 63) / 64, 2);    // 1564 blocks

    // layer 0 (reordered): ax = Â x (pre-scaled bf16 gather); h_a = relu(ax @ W0 + b0)
    aggregate_xb<<<agg_grid, 256, 0, stream>>>((const uint4*)xb, x, offsets, csr, dis, ax);
    gemm64<F_IN, true, false><<<gemm_grid, 128, 0, stream>>>(ax, W0, b0, nullptr, h_a, N_NODES);
    // layer 1: h_tmpb = bf16(dis * (h_a @ W1)); h_bb = bf16(dis * relu(Â... + b1))
    gemm64<F_HID, false, true><<<gemm_grid, 128, 0, stream>>>(h_a, W1, nullptr, dis, h_tmpb, N_NODES);
    aggregate128b<true, true, true><<<agg_grid, 256, 0, stream>>>((const uint4*)h_tmpb, offsets, csr, dis, b1, h_bb);
    // layer 2 (commuted): agg2 = Â h_bb (fp32 out); pool; then @W2 + b2
    aggregate128b<false, false, false><<<agg_grid, 256, 0, stream>>>((const uint4*)h_bb, offsets, csr, dis, nullptr, agg2);

    // pool + layer-2 linear + MLP
    pool16<<<(N_NODES + 15) / 16, 128, 0, stream>>>(agg2, batch, g_acc, g_cnt);
    graph_w2<<<N_GRAPHS, 128, 0, stream>>>(g_acc, g_cnt, W2, b2, g2);
    mlp1<<<N_GRAPHS, N_HID, 0, stream>>>(g2, Wm1, bm1, g_hid);
    mlp2<<<N_GRAPHS, N_OUT, 0, stream>>>(g_hid, Wm2, bm2, (float*)d_out);
}

// Round 15
// 354.143 us; speedup vs baseline: 1.0491x; 1.0491x over previous
//
#include <hip/hip_runtime.h>
#include <hip/hip_bf16.h>
#include <math.h>
#include <stdint.h>

#define N_NODES 50000
#define N_PAD   50048   // padded rows for MFMA tile overrun
#define N_EDGES 800000
#define N_GRAPHS 256
#define F_IN 64
#define F_HID 128
#define N_HID 512
#define N_OUT 256

#define SCAN_B 256
#define SCAN_NBLK ((N_NODES + SCAN_B - 1) / SCAN_B)   // 196

using bf16x8 = __attribute__((ext_vector_type(8))) short;   // MFMA A/B frag (4 VGPRs)
using f32x4  = __attribute__((ext_vector_type(4))) float;   // MFMA C/D frag

// pack two fp32 into a uint holding two bf16 (RNE); low16 = a, high16 = b
__device__ __forceinline__ unsigned int bf16pair(float a, float b) {
    unsigned int ua = __float_as_uint(a);
    unsigned int ub = __float_as_uint(b);
    ua += 0x7fffu + ((ua >> 16) & 1u);
    ub += 0x7fffu + ((ub >> 16) & 1u);
    return (ua >> 16) | (ub & 0xffff0000u);
}
__device__ __forceinline__ float bf16lo(unsigned int u) { return __uint_as_float(u << 16); }
__device__ __forceinline__ float bf16hi(unsigned int u) { return __uint_as_float(u & 0xffff0000u); }

// ---------------------------------------------------------------------------
// K0: xb'[s] = bf16(dis[s] * x[s])  (pre-scaled gather table)
__global__ void cvt_bf16(const float* __restrict__ in, const float* __restrict__ dis,
                         unsigned int* __restrict__ out, int n4) {
    int idx = blockIdx.x * blockDim.x + threadIdx.x;
    if (idx < n4) {
        int node = idx >> 4;                  // 16 float4 per 64-f row
        float d = dis[node];
        float4 v = ((const float4*)in)[idx];
        ((uint2*)out)[idx] = make_uint2(bf16pair(d * v.x, d * v.y),
                                        bf16pair(d * v.z, d * v.w));
    }
}

// K0b: W[K][128] fp32 -> WT[128][K] bf16 (MFMA B-operand table)
__global__ void cvt_wt(const float* __restrict__ W, unsigned short* __restrict__ WTb, int K) {
    int idx = blockIdx.x * blockDim.x + threadIdx.x;
    if (idx < K * 128) {
        int k = idx >> 7, n = idx & 127;
        unsigned int u = __float_as_uint(W[idx]);
        u += 0x7fffu + ((u >> 16) & 1u);
        WTb[n * K + k] = (unsigned short)(u >> 16);
    }
}

// ---------------------------------------------------------------------------
// K1: in-degree count
__global__ void count_deg(const int* __restrict__ ei, int* __restrict__ indeg) {
    int e = blockIdx.x * blockDim.x + threadIdx.x;
    if (e < N_EDGES) atomicAdd(&indeg[ei[N_EDGES + e]], 1);
}

// K2a/K2b/K2c: hierarchical scan
__global__ __launch_bounds__(SCAN_B) void scan_partial(const int* __restrict__ indeg,
                                                       int* __restrict__ blockSums) {
    __shared__ int sdata[SCAN_B];
    int i = blockIdx.x * SCAN_B + threadIdx.x;
    sdata[threadIdx.x] = (i < N_NODES) ? indeg[i] : 0;
    __syncthreads();
    for (int off = SCAN_B / 2; off > 0; off >>= 1) {
        if (threadIdx.x < off) sdata[threadIdx.x] += sdata[threadIdx.x + off];
        __syncthreads();
    }
    if (threadIdx.x == 0) blockSums[blockIdx.x] = sdata[0];
}

__global__ __launch_bounds__(SCAN_B) void scan_block_sums(int* __restrict__ blockSums) {
    __shared__ int buf[SCAN_B];
    int tid = threadIdx.x;
    int v = (tid < SCAN_NBLK) ? blockSums[tid] : 0;
    buf[tid] = v;
    __syncthreads();
    for (int off = 1; off < SCAN_B; off <<= 1) {
        int t = (tid >= off) ? buf[tid - off] : 0;
        __syncthreads();
        buf[tid] += t;
        __syncthreads();
    }
    if (tid < SCAN_NBLK) blockSums[tid] = buf[tid] - v;   // exclusive
}

__global__ __launch_bounds__(SCAN_B) void scan_final(const int* __restrict__ indeg,
                                                     const int* __restrict__ blockSums,
                                                     int* __restrict__ offsets,
                                                     float* __restrict__ dis) {
    __shared__ int buf[SCAN_B];
    int tid = threadIdx.x;
    int i = blockIdx.x * SCAN_B + tid;
    int v = (i < N_NODES) ? indeg[i] : 0;
    if (i < N_NODES) dis[i] = rsqrtf((float)(v + 1));
    buf[tid] = v;
    __syncthreads();
    for (int off = 1; off < SCAN_B; off <<= 1) {
        int t = (tid >= off) ? buf[tid - off] : 0;
        __syncthreads();
        buf[tid] += t;
        __syncthreads();
    }
    if (i < N_NODES) offsets[i] = blockSums[blockIdx.x] + buf[tid] - v;
    if (i == 0) offsets[N_NODES] = N_EDGES;
}

// K3: scatter edges into CSR (by dst). ushort src entries.
__global__ void build_csr(const int* __restrict__ ei, const int* __restrict__ offsets,
                          int* __restrict__ cursor, unsigned short* __restrict__ csr) {
    int e = blockIdx.x * blockDim.x + threadIdx.x;
    if (e < N_EDGES) {
        int s = ei[e];
        int d = ei[N_EDGES + e];
        int pos = atomicAdd(&cursor[d], 1);
        csr[offsets[d] + pos] = (unsigned short)s;
    }
}

// ---------------------------------------------------------------------------
// K4: MFMA GEMM. C[M,128] = A[M,K]@W[K,128], A bf16 [M][K], WT bf16 [128][K].
// 256 thr = 4 waves; wave = 16 rows x 128 cols = 8 mfma 16x16x32 tiles.
// A-frag: A[m=lane&15][k=quad*8+j] (16B load). B-frag: WT[n=lane&15][k=quad*8+j].
// C/D: col=lane&15, row=quad*4+reg. Output packed bf16 via shfl-pair.
template <int K, bool BIASRELU, bool DISSCALE>
__global__ __launch_bounds__(256) void gemm_mfma(const unsigned short* __restrict__ Ab,
                                                 const unsigned short* __restrict__ WTb,
                                                 const float* __restrict__ bias,
                                                 const float* __restrict__ disv,
                                                 unsigned int* __restrict__ outb, int M) {
    int wv = threadIdx.x >> 6;
    int lane = threadIdx.x & 63;
    int m = lane & 15;
    int quad = lane >> 4;
    int row0 = blockIdx.x * 64 + wv * 16;
    f32x4 acc[8];
#pragma unroll
    for (int t = 0; t < 8; ++t) acc[t] = (f32x4){0.f, 0.f, 0.f, 0.f};
#pragma unroll
    for (int ks = 0; ks < K; ks += 32) {
        bf16x8 af = *(const bf16x8*)&Ab[(size_t)(row0 + m) * K + ks + quad * 8];
#pragma unroll
        for (int t = 0; t < 8; ++t) {
            bf16x8 bf = *(const bf16x8*)&WTb[(size_t)(t * 16 + m) * K + ks + quad * 8];
            acc[t] = __builtin_amdgcn_mfma_f32_16x16x32_bf16(af, bf, acc[t], 0, 0, 0);
        }
    }
    float dr[4];
#pragma unroll
    for (int r = 0; r < 4; ++r) {
        int row = row0 + quad * 4 + r;
        dr[r] = DISSCALE ? ((row < M) ? disv[row] : 0.f) : 1.f;
    }
#pragma unroll
    for (int t = 0; t < 8; ++t) {
        int col = t * 16 + m;
        float bcol = 0.f;
        if (BIASRELU) bcol = bias[col];
#pragma unroll
        for (int r = 0; r < 4; ++r) {
            float v = acc[t][r];
            if (BIASRELU) v = fmaxf(v + bcol, 0.f);
            if (DISSCALE) v = v * dr[r];
            float vn = __shfl_xor(v, 1, 64);    // neighbor col's value
            if ((m & 1) == 0) {
                int row = row0 + quad * 4 + r;
                if (row < M)
                    outb[(size_t)row * 64 + (col >> 1)] = bf16pair(v, vn);
            }
        }
    }
}

// ---------------------------------------------------------------------------
// K5a: F=128 aggregate over PRE-SCALED bf16 table (hb'[s] = dis[s]*h[s]).
// uint2 lanes, 2 edges/inst, xor-32 combine. fp32 accumulate.
template <bool RELU, bool BIAS, bool BF16OUT>
__global__ __launch_bounds__(256) void aggregate128b(const uint2* __restrict__ hb2,
                                                     const int* __restrict__ offsets,
                                                     const unsigned short* __restrict__ csr,
                                                     const float* __restrict__ dis,
                                                     const float* __restrict__ bias,
                                                     void* __restrict__ outp) {
    int wave = threadIdx.x >> 6;
    int lane = threadIdx.x & 63;
    int i = blockIdx.x * 4 + wave;
    if (i >= N_NODES) return;
    int sub = lane >> 5;
    int q   = lane & 31;
    float a0 = 0.f, a1 = 0.f, a2 = 0.f, a3 = 0.f;
    int j = offsets[i], s1 = offsets[i + 1];
    for (; j < s1; j += 16) {
        int s[8]; float m[8];
#pragma unroll
        for (int u = 0; u < 8; ++u) {
            int e = j + 2 * u + sub;
            bool valid = e < s1;
            s[u] = valid ? (int)csr[e] : 0;
            m[u] = valid ? 1.f : 0.f;
        }
        uint2 r[8];
#pragma unroll
        for (int u = 0; u < 8; ++u) r[u] = hb2[(size_t)s[u] * 32 + q];
#pragma unroll
        for (int u = 0; u < 8; ++u) {
            a0 += m[u] * bf16lo(r[u].x);
            a1 += m[u] * bf16hi(r[u].x);
            a2 += m[u] * bf16lo(r[u].y);
            a3 += m[u] * bf16hi(r[u].y);
        }
    }
    a0 += __shfl_xor(a0, 32, 64);
    a1 += __shfl_xor(a1, 32, 64);
    a2 += __shfl_xor(a2, 32, 64);
    a3 += __shfl_xor(a3, 32, 64);
    uint2 su = hb2[(size_t)i * 32 + q];     // self: weight 1 in scaled domain
    a0 += bf16lo(su.x);
    a1 += bf16hi(su.x);
    a2 += bf16lo(su.y);
    a3 += bf16hi(su.y);
    float dii = dis[i];
    a0 *= dii; a1 *= dii; a2 *= dii; a3 *= dii;
    if (BIAS) {
        float4 b = ((const float4*)bias)[q];
        a0 += b.x; a1 += b.y; a2 += b.z; a3 += b.w;
    }
    if (RELU) {
        a0 = fmaxf(a0, 0.f); a1 = fmaxf(a1, 0.f);
        a2 = fmaxf(a2, 0.f); a3 = fmaxf(a3, 0.f);
    }
    if (sub == 0) {
        if (BF16OUT)   // next gather table: pre-scale by dis[i]
            ((uint2*)outp)[(size_t)i * 32 + q] =
                make_uint2(bf16pair(dii * a0, dii * a1), bf16pair(dii * a2, dii * a3));
        else
            ((float4*)outp)[(size_t)i * 32 + q] = make_float4(a0, a1, a2, a3);
    }
}

// K5b: F=64 aggregate over pre-scaled bf16 x-table. uint2 lanes, 4 edges/inst.
// Output: PLAIN bf16 (axb) — feeds the MFMA GEMM A operand.
__global__ __launch_bounds__(256) void aggregate_xb(const uint2* __restrict__ xb2,
                                                    const float* __restrict__ x,
                                                    const int* __restrict__ offsets,
                                                    const unsigned short* __restrict__ csr,
                                                    const float* __restrict__ dis,
                                                    unsigned int* __restrict__ outb) {
    int wave = threadIdx.x >> 6;
    int lane = threadIdx.x & 63;
    int i = blockIdx.x * 4 + wave;
    if (i >= N_NODES) return;
    int sub = lane >> 4;              // 0..3: which edge of the quad
    int q   = lane & 15;              // uint2 index within the 16-uint2 row
    float a0 = 0.f, a1 = 0.f, a2 = 0.f, a3 = 0.f;
    int j = offsets[i], s1 = offsets[i + 1];
    for (; j < s1; j += 32) {
        int s[8]; float m[8];
#pragma unroll
        for (int u = 0; u < 8; ++u) {
            int e = j + 4 * u + sub;
            bool valid = e < s1;
            s[u] = valid ? (int)csr[e] : 0;
            m[u] = valid ? 1.f : 0.f;
        }
        uint2 r[8];
#pragma unroll
        for (int u = 0; u < 8; ++u) r[u] = xb2[(size_t)s[u] * 16 + q];
#pragma unroll
        for (int u = 0; u < 8; ++u) {
            a0 += m[u] * bf16lo(r[u].x);
            a1 += m[u] * bf16hi(r[u].x);
            a2 += m[u] * bf16lo(r[u].y);
            a3 += m[u] * bf16hi(r[u].y);
        }
    }
    a0 += __shfl_xor(a0, 16, 64);  a1 += __shfl_xor(a1, 16, 64);
    a2 += __shfl_xor(a2, 16, 64);  a3 += __shfl_xor(a3, 16, 64);
    a0 += __shfl_xor(a0, 32, 64);  a1 += __shfl_xor(a1, 32, 64);
    a2 += __shfl_xor(a2, 32, 64);  a3 += __shfl_xor(a3, 32, 64);
    float dii = dis[i];
    float d2 = dii * dii;
    float4 sx = ((const float4*)x)[(size_t)i * 16 + q];   // self in fp32
    a0 = dii * a0 + d2 * sx.x;
    a1 = dii * a1 + d2 * sx.y;
    a2 = dii * a2 + d2 * sx.z;
    a3 = dii * a3 + d2 * sx.w;
    if (sub == 0)
        ((uint2*)outb)[(size_t)i * 16 + q] = make_uint2(bf16pair(a0, a1), bf16pair(a2, a3));
}

// ---------------------------------------------------------------------------
// K6: mean-pool (batch is sorted -> register-accumulate 16 nodes, flush on change)
__global__ __launch_bounds__(128) void pool16(const float* __restrict__ h,
                                              const int* __restrict__ batch,
                                              float* __restrict__ g_acc,
                                              float* __restrict__ g_cnt) {
    const int NB = 16;
    int base = blockIdx.x * NB;
    int f = threadIdx.x;
    float acc = 0.f;
    int cur = -1, cnt = 0;
    for (int n = 0; n < NB; ++n) {
        int i = base + n;
        if (i >= N_NODES) break;
        int b = batch[i];
        if (b != cur) {
            if (cur >= 0) {
                atomicAdd(&g_acc[(size_t)cur * F_HID + f], acc);
                if (f == 0) atomicAdd(&g_cnt[cur], (float)cnt);
            }
            cur = b; acc = 0.f; cnt = 0;
        }
        acc += h[(size_t)i * F_HID + f];
        cnt++;
    }
    if (cur >= 0) {
        atomicAdd(&g_acc[(size_t)cur * F_HID + f], acc);
        if (f == 0) atomicAdd(&g_cnt[cur], (float)cnt);
    }
}

// K6b: g2 = (g_acc/cnt) @ W2 + b2
__global__ __launch_bounds__(128) void graph_w2(const float* __restrict__ g_acc,
                                                const float* __restrict__ g_cnt,
                                                const float* __restrict__ W2,
                                                const float* __restrict__ b2,
                                                float* __restrict__ g2) {
    __shared__ float row[F_HID];
    int g = blockIdx.x;
    int t = threadIdx.x;
    float c = g_cnt[g];
    row[t] = g_acc[(size_t)g * F_HID + t] / fmaxf(c, 1.0f);
    __syncthreads();
    float acc = b2[t];
    for (int k = 0; k < F_HID; ++k) acc += row[k] * W2[(size_t)k * F_HID + t];
    g2[(size_t)g * F_HID + t] = acc;
}

// K7: g_hid = relu(g2 @ Wm1 + bm1)
__global__ __launch_bounds__(512) void mlp1(const float* __restrict__ g2,
                                            const float* __restrict__ Wm1,
                                            const float* __restrict__ bm1,
                                            float* __restrict__ g_hid) {
    __shared__ float row[F_HID];
    int g = blockIdx.x;
    int t = threadIdx.x;
    if (t < F_HID) row[t] = g2[(size_t)g * F_HID + t];
    __syncthreads();
    float acc = bm1[t];
    for (int k = 0; k < F_HID; ++k) acc += row[k] * Wm1[(size_t)k * N_HID + t];
    g_hid[(size_t)g * N_HID + t] = fmaxf(acc, 0.f);
}

// K8: out = g_hid @ Wm2 + bm2
__global__ __launch_bounds__(256) void mlp2(const float* __restrict__ g_hid,
                                            const float* __restrict__ Wm2,
                                            const float* __restrict__ bm2,
                                            float* __restrict__ out) {
    __shared__ float row[N_HID];
    int g = blockIdx.x;
    int t = threadIdx.x;
    row[t] = g_hid[(size_t)g * N_HID + t];
    row[t + 256] = g_hid[(size_t)g * N_HID + t + 256];
    __syncthreads();
    float acc = bm2[t];
    for (int k = 0; k < N_HID; ++k) acc += row[k] * Wm2[(size_t)k * N_OUT + t];
    out[(size_t)g * N_OUT + t] = acc;
}

// ---------------------------------------------------------------------------
extern "C" void kernel_launch(void* const* d_in, const int* in_sizes, int n_in,
                              void* d_out, int out_size, void* d_ws, size_t ws_size,
                              hipStream_t stream) {
    const float* x   = (const float*)d_in[0];
    const int* ei    = (const int*)d_in[1];     // [2, E] int32
    const int* batch = (const int*)d_in[2];
    const float* W0 = (const float*)d_in[3];  const float* b0 = (const float*)d_in[4];
    const float* W1 = (const float*)d_in[5];  const float* b1 = (const float*)d_in[6];
    const float* W2 = (const float*)d_in[7];  const float* b2 = (const float*)d_in[8];
    const float* Wm1 = (const float*)d_in[9];  const float* bm1 = (const float*)d_in[10];
    const float* Wm2 = (const float*)d_in[11]; const float* bm2 = (const float*)d_in[12];

    // bump allocator on d_ws, 256B-aligned slots
    char* p = (char*)d_ws;
    auto alloc = [&](size_t bytes) -> char* {
        char* r = p;
        p += (bytes + 255) & ~(size_t)255;
        return r;
    };
    // zero-init region (contiguous in allocation order)
    int*   indeg  = (int*)alloc(N_NODES * 4);
    int*   cursor = (int*)alloc(N_NODES * 4);
    float* g_acc  = (float*)alloc((size_t)N_GRAPHS * F_HID * 4);
    float* g_cnt  = (float*)alloc(N_GRAPHS * 4);
    size_t zero_bytes = (size_t)(p - (char*)indeg);
    // rest
    int*   blockSums = (int*)alloc(SCAN_NBLK * 4);
    int*   offsets = (int*)alloc((N_NODES + 1) * 4);
    float* dis     = (float*)alloc(N_NODES * 4);
    unsigned short* csr = (unsigned short*)alloc((size_t)N_EDGES * 2);
    unsigned int* xb     = (unsigned int*)alloc((size_t)N_NODES * F_IN / 2 * 4);   // bf16 x' (dis-scaled)
    unsigned int* axb    = (unsigned int*)alloc((size_t)N_PAD * F_IN / 2 * 4);     // bf16 Âx (plain)
    unsigned int* h_ab   = (unsigned int*)alloc((size_t)N_PAD * F_HID / 2 * 4);    // bf16 h_a (plain)
    unsigned int* h_tmpb = (unsigned int*)alloc((size_t)N_PAD * F_HID / 2 * 4);    // bf16 (dis-scaled)
    unsigned int* h_bb   = (unsigned int*)alloc((size_t)N_NODES * F_HID / 2 * 4);  // bf16 (dis-scaled)
    unsigned short* W0Tb = (unsigned short*)alloc((size_t)128 * F_IN * 2);
    unsigned short* W1Tb = (unsigned short*)alloc((size_t)128 * F_HID * 2);
    float*        agg2   = (float*)alloc((size_t)N_NODES * F_HID * 4);
    float*        g2     = (float*)alloc((size_t)N_GRAPHS * F_HID * 4);
    float*        g_hid  = (float*)alloc((size_t)N_GRAPHS * N_HID * 4);
    (void)ws_size; (void)in_sizes; (void)n_in; (void)out_size;

    (void)hipMemsetAsync(indeg, 0, zero_bytes, stream);

    count_deg<<<(N_EDGES + 255) / 256, 256, 0, stream>>>(ei, indeg);
    scan_partial<<<SCAN_NBLK, SCAN_B, 0, stream>>>(indeg, blockSums);
    scan_block_sums<<<1, SCAN_B, 0, stream>>>(blockSums);
    scan_final<<<SCAN_NBLK, SCAN_B, 0, stream>>>(indeg, blockSums, offsets, dis);
    build_csr<<<(N_EDGES + 255) / 256, 256, 0, stream>>>(ei, offsets, cursor, csr);
    cvt_bf16<<<(N_NODES * F_IN / 4 + 255) / 256, 256, 0, stream>>>(x, dis, xb, N_NODES * F_IN / 4);
    cvt_wt<<<(F_IN * 128 + 255) / 256, 256, 0, stream>>>(W0, W0Tb, F_IN);
    cvt_wt<<<(F_HID * 128 + 255) / 256, 256, 0, stream>>>(W1, W1Tb, F_HID);

    int agg_grid = (N_NODES + 3) / 4;          // 4 nodes (waves) per block
    int mfma_grid = (N_NODES + 63) / 64;       // 782 blocks

    // layer 0 (reordered): axb = bf16(Â x); h_ab = bf16(relu(axb @ W0 + b0))
    aggregate_xb<<<agg_grid, 256, 0, stream>>>((const uint2*)xb, x, offsets, csr, dis, axb);
    gemm_mfma<F_IN, true, false><<<mfma_grid, 256, 0, stream>>>(
        (const unsigned short*)axb, W0Tb, b0, nullptr, h_ab, N_NODES);
    // layer 1: h_tmpb = bf16(dis * (h_ab @ W1)); h_bb = bf16(dis * relu(Â.. + b1))
    gemm_mfma<F_HID, false, true><<<mfma_grid, 256, 0, stream>>>(
        (const unsigned short*)h_ab, W1Tb, nullptr, dis, h_tmpb, N_NODES);
    aggregate128b<true, true, true><<<agg_grid, 256, 0, stream>>>(
        (const uint2*)h_tmpb, offsets, csr, dis, b1, h_bb);
    // layer 2 (commuted): agg2 = Â h_bb (fp32); pool; then @W2 + b2
    aggregate128b<false, false, false><<<agg_grid, 256, 0, stream>>>(
        (const uint2*)h_bb, offsets, csr, dis, nullptr, agg2);

    // pool + layer-2 linear + MLP
    pool16<<<(N_NODES + 15) / 16, 128, 0, stream>>>(agg2, batch, g_acc, g_cnt);
    graph_w2<<<N_GRAPHS, 128, 0, stream>>>(g_acc, g_cnt, W2, b2, g2);
    mlp1<<<N_GRAPHS, N_HID, 0, stream>>>(g2, Wm1, bm1, g_hid);
    mlp2<<<N_GRAPHS, N_OUT, 0, stream>>>(g_hid, Wm2, bm2, (float*)d_out);
}

// Round 16
// 336.784 us; speedup vs baseline: 1.1032x; 1.0515x over previous
//
#include <hip/hip_runtime.h>
#include <hip/hip_bf16.h>
#include <math.h>
#include <stdint.h>

#define N_NODES 50000
#define N_PAD   50048   // padded rows for MFMA tile overrun
#define N_EDGES 800000
#define N_GRAPHS 256
#define F_IN 64
#define F_HID 128
#define N_HID 512
#define N_OUT 256

#define SCAN_B 256
#define SCAN_NBLK ((N_NODES + SCAN_B - 1) / SCAN_B)   // 196

using bf16x8 = __attribute__((ext_vector_type(8))) short;   // MFMA A/B frag (4 VGPRs)
using f32x4  = __attribute__((ext_vector_type(4))) float;   // MFMA C/D frag

// pack two fp32 into a uint holding two bf16 (RNE); low16 = a, high16 = b
__device__ __forceinline__ unsigned int bf16pair(float a, float b) {
    unsigned int ua = __float_as_uint(a);
    unsigned int ub = __float_as_uint(b);
    ua += 0x7fffu + ((ua >> 16) & 1u);
    ub += 0x7fffu + ((ub >> 16) & 1u);
    return (ua >> 16) | (ub & 0xffff0000u);
}
__device__ __forceinline__ float bf16lo(unsigned int u) { return __uint_as_float(u << 16); }
__device__ __forceinline__ float bf16hi(unsigned int u) { return __uint_as_float(u & 0xffff0000u); }

// ---------------------------------------------------------------------------
// K0: xb'[s] = bf16(dis[s] * x[s])  (pre-scaled gather table)
__global__ void cvt_bf16(const float* __restrict__ in, const float* __restrict__ dis,
                         unsigned int* __restrict__ out, int n4) {
    int idx = blockIdx.x * blockDim.x + threadIdx.x;
    if (idx < n4) {
        int node = idx >> 4;                  // 16 float4 per 64-f row
        float d = dis[node];
        float4 v = ((const float4*)in)[idx];
        ((uint2*)out)[idx] = make_uint2(bf16pair(d * v.x, d * v.y),
                                        bf16pair(d * v.z, d * v.w));
    }
}

// K0b: both weight tables fp32 [K][128] -> bf16 [128][K] in one dispatch
__global__ void cvt_wt2(const float* __restrict__ W0, unsigned short* __restrict__ W0Tb,
                        const float* __restrict__ W1, unsigned short* __restrict__ W1Tb) {
    int idx = blockIdx.x * blockDim.x + threadIdx.x;
    const int N0 = F_IN * 128;
    const int N1 = F_HID * 128;
    if (idx < N0) {
        int k = idx >> 7, n = idx & 127;
        unsigned int u = __float_as_uint(W0[idx]);
        u += 0x7fffu + ((u >> 16) & 1u);
        W0Tb[n * F_IN + k] = (unsigned short)(u >> 16);
    } else if (idx < N0 + N1) {
        int j = idx - N0;
        int k = j >> 7, n = j & 127;
        unsigned int u = __float_as_uint(W1[j]);
        u += 0x7fffu + ((u >> 16) & 1u);
        W1Tb[n * F_HID + k] = (unsigned short)(u >> 16);
    }
}

// ---------------------------------------------------------------------------
// K1: in-degree count
__global__ void count_deg(const int* __restrict__ ei, int* __restrict__ indeg) {
    int e = blockIdx.x * blockDim.x + threadIdx.x;
    if (e < N_EDGES) atomicAdd(&indeg[ei[N_EDGES + e]], 1);
}

// K2a/K2b/K2c: hierarchical scan
__global__ __launch_bounds__(SCAN_B) void scan_partial(const int* __restrict__ indeg,
                                                       int* __restrict__ blockSums) {
    __shared__ int sdata[SCAN_B];
    int i = blockIdx.x * SCAN_B + threadIdx.x;
    sdata[threadIdx.x] = (i < N_NODES) ? indeg[i] : 0;
    __syncthreads();
    for (int off = SCAN_B / 2; off > 0; off >>= 1) {
        if (threadIdx.x < off) sdata[threadIdx.x] += sdata[threadIdx.x + off];
        __syncthreads();
    }
    if (threadIdx.x == 0) blockSums[blockIdx.x] = sdata[0];
}

__global__ __launch_bounds__(SCAN_B) void scan_block_sums(int* __restrict__ blockSums) {
    __shared__ int buf[SCAN_B];
    int tid = threadIdx.x;
    int v = (tid < SCAN_NBLK) ? blockSums[tid] : 0;
    buf[tid] = v;
    __syncthreads();
    for (int off = 1; off < SCAN_B; off <<= 1) {
        int t = (tid >= off) ? buf[tid - off] : 0;
        __syncthreads();
        buf[tid] += t;
        __syncthreads();
    }
    if (tid < SCAN_NBLK) blockSums[tid] = buf[tid] - v;   // exclusive
}

__global__ __launch_bounds__(SCAN_B) void scan_final(const int* __restrict__ indeg,
                                                     const int* __restrict__ blockSums,
                                                     int* __restrict__ offsets,
                                                     float* __restrict__ dis) {
    __shared__ int buf[SCAN_B];
    int tid = threadIdx.x;
    int i = blockIdx.x * SCAN_B + tid;
    int v = (i < N_NODES) ? indeg[i] : 0;
    if (i < N_NODES) dis[i] = rsqrtf((float)(v + 1));
    buf[tid] = v;
    __syncthreads();
    for (int off = 1; off < SCAN_B; off <<= 1) {
        int t = (tid >= off) ? buf[tid - off] : 0;
        __syncthreads();
        buf[tid] += t;
        __syncthreads();
    }
    if (i < N_NODES) offsets[i] = blockSums[blockIdx.x] + buf[tid] - v;
    if (i == 0) offsets[N_NODES] = N_EDGES;
}

// K3: scatter edges into CSR (by dst). ushort src entries. Reuses indeg as
// the cursor via atomicSub (indeg is dead after scan_final).
__global__ void build_csr(const int* __restrict__ ei, const int* __restrict__ offsets,
                          int* __restrict__ indeg, unsigned short* __restrict__ csr) {
    int e = blockIdx.x * blockDim.x + threadIdx.x;
    if (e < N_EDGES) {
        int s = ei[e];
        int d = ei[N_EDGES + e];
        int pos = atomicSub(&indeg[d], 1) - 1;   // deg-1 .. 0
        csr[offsets[d] + pos] = (unsigned short)s;
    }
}

// ---------------------------------------------------------------------------
// K4: MFMA GEMM. C[M,128] = A[M,K]@W[K,128], A bf16 [M][K], WT bf16 [128][K].
// 256 thr = 4 waves; wave = 16 rows x 128 cols = 8 mfma 16x16x32 tiles.
template <int K, bool BIASRELU, bool DISSCALE>
__global__ __launch_bounds__(256) void gemm_mfma(const unsigned short* __restrict__ Ab,
                                                 const unsigned short* __restrict__ WTb,
                                                 const float* __restrict__ bias,
                                                 const float* __restrict__ disv,
                                                 unsigned int* __restrict__ outb, int M) {
    int wv = threadIdx.x >> 6;
    int lane = threadIdx.x & 63;
    int m = lane & 15;
    int quad = lane >> 4;
    int row0 = blockIdx.x * 64 + wv * 16;
    f32x4 acc[8];
#pragma unroll
    for (int t = 0; t < 8; ++t) acc[t] = (f32x4){0.f, 0.f, 0.f, 0.f};
#pragma unroll
    for (int ks = 0; ks < K; ks += 32) {
        bf16x8 af = *(const bf16x8*)&Ab[(size_t)(row0 + m) * K + ks + quad * 8];
#pragma unroll
        for (int t = 0; t < 8; ++t) {
            bf16x8 bf = *(const bf16x8*)&WTb[(size_t)(t * 16 + m) * K + ks + quad * 8];
            acc[t] = __builtin_amdgcn_mfma_f32_16x16x32_bf16(af, bf, acc[t], 0, 0, 0);
        }
    }
    float dr[4];
#pragma unroll
    for (int r = 0; r < 4; ++r) {
        int row = row0 + quad * 4 + r;
        dr[r] = DISSCALE ? ((row < M) ? disv[row] : 0.f) : 1.f;
    }
#pragma unroll
    for (int t = 0; t < 8; ++t) {
        int col = t * 16 + m;
        float bcol = 0.f;
        if (BIASRELU) bcol = bias[col];
#pragma unroll
        for (int r = 0; r < 4; ++r) {
            float v = acc[t][r];
            if (BIASRELU) v = fmaxf(v + bcol, 0.f);
            if (DISSCALE) v = v * dr[r];
            float vn = __shfl_xor(v, 1, 64);    // neighbor col's value
            if ((m & 1) == 0) {
                int row = row0 + quad * 4 + r;
                if (row < M)
                    outb[(size_t)row * 64 + (col >> 1)] = bf16pair(v, vn);
            }
        }
    }
}

// ---------------------------------------------------------------------------
// K5a: F=128 aggregate over PRE-SCALED bf16 table (hb'[s] = dis[s]*h[s]).
// uint2 lanes, 2 edges/inst, xor-32 combine; mask-free main loop + masked tail.
// SCALEOUT: multiply output by dis[i] (next gather table). Output always bf16.
template <bool RELU, bool BIAS, bool SCALEOUT>
__global__ __launch_bounds__(256) void aggregate128b(const uint2* __restrict__ hb2,
                                                     const int* __restrict__ offsets,
                                                     const unsigned short* __restrict__ csr,
                                                     const float* __restrict__ dis,
                                                     const float* __restrict__ bias,
                                                     unsigned int* __restrict__ outb) {
    int wave = threadIdx.x >> 6;
    int lane = threadIdx.x & 63;
    int i = blockIdx.x * 4 + wave;
    if (i >= N_NODES) return;
    int sub = lane >> 5;
    int q   = lane & 31;
    float a0 = 0.f, a1 = 0.f, a2 = 0.f, a3 = 0.f;
    int j = offsets[i], s1 = offsets[i + 1];
    for (; j + 16 <= s1; j += 16) {       // full chunks: no masks
        int s[8];
#pragma unroll
        for (int u = 0; u < 8; ++u) s[u] = (int)csr[j + 2 * u + sub];
        uint2 r[8];
#pragma unroll
        for (int u = 0; u < 8; ++u) r[u] = hb2[(size_t)s[u] * 32 + q];
#pragma unroll
        for (int u = 0; u < 8; ++u) {
            a0 += bf16lo(r[u].x);  a1 += bf16hi(r[u].x);
            a2 += bf16lo(r[u].y);  a3 += bf16hi(r[u].y);
        }
    }
    if (j < s1) {                          // masked tail chunk
        int s[8]; float m[8];
#pragma unroll
        for (int u = 0; u < 8; ++u) {
            int e = j + 2 * u + sub;
            bool valid = e < s1;
            s[u] = valid ? (int)csr[e] : 0;
            m[u] = valid ? 1.f : 0.f;
        }
        uint2 r[8];
#pragma unroll
        for (int u = 0; u < 8; ++u) r[u] = hb2[(size_t)s[u] * 32 + q];
#pragma unroll
        for (int u = 0; u < 8; ++u) {
            a0 += m[u] * bf16lo(r[u].x);  a1 += m[u] * bf16hi(r[u].x);
            a2 += m[u] * bf16lo(r[u].y);  a3 += m[u] * bf16hi(r[u].y);
        }
    }
    a0 += __shfl_xor(a0, 32, 64);
    a1 += __shfl_xor(a1, 32, 64);
    a2 += __shfl_xor(a2, 32, 64);
    a3 += __shfl_xor(a3, 32, 64);
    uint2 su = hb2[(size_t)i * 32 + q];     // self: weight 1 in scaled domain
    a0 += bf16lo(su.x);  a1 += bf16hi(su.x);
    a2 += bf16lo(su.y);  a3 += bf16hi(su.y);
    float dii = dis[i];
    a0 *= dii; a1 *= dii; a2 *= dii; a3 *= dii;
    if (BIAS) {
        float4 b = ((const float4*)bias)[q];
        a0 += b.x; a1 += b.y; a2 += b.z; a3 += b.w;
    }
    if (RELU) {
        a0 = fmaxf(a0, 0.f); a1 = fmaxf(a1, 0.f);
        a2 = fmaxf(a2, 0.f); a3 = fmaxf(a3, 0.f);
    }
    if (sub == 0) {
        float sc = SCALEOUT ? dii : 1.f;
        ((uint2*)outb)[(size_t)i * 32 + q] =
            make_uint2(bf16pair(sc * a0, sc * a1), bf16pair(sc * a2, sc * a3));
    }
}

// K5b: F=64 aggregate over pre-scaled bf16 x-table. uint2 lanes, 4 edges/inst.
// Output: PLAIN bf16 (axb) — feeds the MFMA GEMM A operand.
__global__ __launch_bounds__(256) void aggregate_xb(const uint2* __restrict__ xb2,
                                                    const float* __restrict__ x,
                                                    const int* __restrict__ offsets,
                                                    const unsigned short* __restrict__ csr,
                                                    const float* __restrict__ dis,
                                                    unsigned int* __restrict__ outb) {
    int wave = threadIdx.x >> 6;
    int lane = threadIdx.x & 63;
    int i = blockIdx.x * 4 + wave;
    if (i >= N_NODES) return;
    int sub = lane >> 4;              // 0..3: which edge of the quad
    int q   = lane & 15;              // uint2 index within the 16-uint2 row
    float a0 = 0.f, a1 = 0.f, a2 = 0.f, a3 = 0.f;
    int j = offsets[i], s1 = offsets[i + 1];
    for (; j + 32 <= s1; j += 32) {   // full chunks: no masks
        int s[8];
#pragma unroll
        for (int u = 0; u < 8; ++u) s[u] = (int)csr[j + 4 * u + sub];
        uint2 r[8];
#pragma unroll
        for (int u = 0; u < 8; ++u) r[u] = xb2[(size_t)s[u] * 16 + q];
#pragma unroll
        for (int u = 0; u < 8; ++u) {
            a0 += bf16lo(r[u].x);  a1 += bf16hi(r[u].x);
            a2 += bf16lo(r[u].y);  a3 += bf16hi(r[u].y);
        }
    }
    if (j < s1) {                      // masked tail chunk
        int s[8]; float m[8];
#pragma unroll
        for (int u = 0; u < 8; ++u) {
            int e = j + 4 * u + sub;
            bool valid = e < s1;
            s[u] = valid ? (int)csr[e] : 0;
            m[u] = valid ? 1.f : 0.f;
        }
        uint2 r[8];
#pragma unroll
        for (int u = 0; u < 8; ++u) r[u] = xb2[(size_t)s[u] * 16 + q];
#pragma unroll
        for (int u = 0; u < 8; ++u) {
            a0 += m[u] * bf16lo(r[u].x);  a1 += m[u] * bf16hi(r[u].x);
            a2 += m[u] * bf16lo(r[u].y);  a3 += m[u] * bf16hi(r[u].y);
        }
    }
    a0 += __shfl_xor(a0, 16, 64);  a1 += __shfl_xor(a1, 16, 64);
    a2 += __shfl_xor(a2, 16, 64);  a3 += __shfl_xor(a3, 16, 64);
    a0 += __shfl_xor(a0, 32, 64);  a1 += __shfl_xor(a1, 32, 64);
    a2 += __shfl_xor(a2, 32, 64);  a3 += __shfl_xor(a3, 32, 64);
    float dii = dis[i];
    float d2 = dii * dii;
    float4 sx = ((const float4*)x)[(size_t)i * 16 + q];   // self in fp32
    a0 = dii * a0 + d2 * sx.x;
    a1 = dii * a1 + d2 * sx.y;
    a2 = dii * a2 + d2 * sx.z;
    a3 = dii * a3 + d2 * sx.w;
    if (sub == 0)
        ((uint2*)outb)[(size_t)i * 16 + q] = make_uint2(bf16pair(a0, a1), bf16pair(a2, a3));
}

// ---------------------------------------------------------------------------
// K6: mean-pool over bf16 table (batch sorted -> register-accumulate, flush on change)
__global__ __launch_bounds__(128) void pool16(const unsigned int* __restrict__ hb,
                                              const int* __restrict__ batch,
                                              float* __restrict__ g_acc,
                                              float* __restrict__ g_cnt) {
    const int NB = 16;
    int base = blockIdx.x * NB;
    int f = threadIdx.x;              // feature 0..127
    int uidx = f >> 1;                // uint index within 64-uint row
    bool hi = f & 1;
    float acc = 0.f;
    int cur = -1, cnt = 0;
    for (int n = 0; n < NB; ++n) {
        int i = base + n;
        if (i >= N_NODES) break;
        int b = batch[i];
        if (b != cur) {
            if (cur >= 0) {
                atomicAdd(&g_acc[(size_t)cur * F_HID + f], acc);
                if (f == 0) atomicAdd(&g_cnt[cur], (float)cnt);
            }
            cur = b; acc = 0.f; cnt = 0;
        }
        unsigned int u = hb[(size_t)i * 64 + uidx];
        acc += hi ? bf16hi(u) : bf16lo(u);
        cnt++;
    }
    if (cur >= 0) {
        atomicAdd(&g_acc[(size_t)cur * F_HID + f], acc);
        if (f == 0) atomicAdd(&g_cnt[cur], (float)cnt);
    }
}

// ---------------------------------------------------------------------------
// K7: fused graph head: g2 = (g_acc/cnt)@W2 + b2; g_hid = relu(g2@Wm1+bm1);
// out = g_hid@Wm2 + bm2.  One block per graph, 512 threads.
__global__ __launch_bounds__(512) void fused_mlp(const float* __restrict__ g_acc,
                                                 const float* __restrict__ g_cnt,
                                                 const float* __restrict__ W2,
                                                 const float* __restrict__ b2,
                                                 const float* __restrict__ Wm1,
                                                 const float* __restrict__ bm1,
                                                 const float* __restrict__ Wm2,
                                                 const float* __restrict__ bm2,
                                                 float* __restrict__ out) {
    __shared__ float pool_row[F_HID];
    __shared__ float g2row[F_HID];
    __shared__ float hid[N_HID];
    int g = blockIdx.x;
    int t = threadIdx.x;              // 0..511
    if (t < F_HID) {
        float c = g_cnt[g];
        pool_row[t] = g_acc[(size_t)g * F_HID + t] / fmaxf(c, 1.0f);
    }
    __syncthreads();
    if (t < F_HID) {
        float acc = b2[t];
        for (int k = 0; k < F_HID; ++k) acc += pool_row[k] * W2[(size_t)k * F_HID + t];
        g2row[t] = acc;
    }
    __syncthreads();
    {
        float acc = bm1[t];
        for (int k = 0; k < F_HID; ++k) acc += g2row[k] * Wm1[(size_t)k * N_HID + t];
        hid[t] = fmaxf(acc, 0.f);
    }
    __syncthreads();
    if (t < N_OUT) {
        float acc = bm2[t];
        for (int k = 0; k < N_HID; ++k) acc += hid[k] * Wm2[(size_t)k * N_OUT + t];
        out[(size_t)g * N_OUT + t] = acc;
    }
}

// ---------------------------------------------------------------------------
extern "C" void kernel_launch(void* const* d_in, const int* in_sizes, int n_in,
                              void* d_out, int out_size, void* d_ws, size_t ws_size,
                              hipStream_t stream) {
    const float* x   = (const float*)d_in[0];
    const int* ei    = (const int*)d_in[1];     // [2, E] int32
    const int* batch = (const int*)d_in[2];
    const float* W0 = (const float*)d_in[3];  const float* b0 = (const float*)d_in[4];
    const float* W1 = (const float*)d_in[5];  const float* b1 = (const float*)d_in[6];
    const float* W2 = (const float*)d_in[7];  const float* b2 = (const float*)d_in[8];
    const float* Wm1 = (const float*)d_in[9];  const float* bm1 = (const float*)d_in[10];
    const float* Wm2 = (const float*)d_in[11]; const float* bm2 = (const float*)d_in[12];

    // bump allocator on d_ws, 256B-aligned slots
    char* p = (char*)d_ws;
    auto alloc = [&](size_t bytes) -> char* {
        char* r = p;
        p += (bytes + 255) & ~(size_t)255;
        return r;
    };
    // zero-init region (contiguous in allocation order)
    int*   indeg  = (int*)alloc(N_NODES * 4);
    float* g_acc  = (float*)alloc((size_t)N_GRAPHS * F_HID * 4);
    float* g_cnt  = (float*)alloc(N_GRAPHS * 4);
    size_t zero_bytes = (size_t)(p - (char*)indeg);
    // rest
    int*   blockSums = (int*)alloc(SCAN_NBLK * 4);
    int*   offsets = (int*)alloc((N_NODES + 1) * 4);
    float* dis     = (float*)alloc(N_NODES * 4);
    unsigned short* csr = (unsigned short*)alloc((size_t)N_EDGES * 2);
    unsigned int* xb     = (unsigned int*)alloc((size_t)N_NODES * F_IN / 2 * 4);   // bf16 x' (dis-scaled)
    unsigned int* axb    = (unsigned int*)alloc((size_t)N_PAD * F_IN / 2 * 4);     // bf16 Âx (plain)
    unsigned int* h_ab   = (unsigned int*)alloc((size_t)N_PAD * F_HID / 2 * 4);    // bf16 h_a (plain)
    unsigned int* h_tmpb = (unsigned int*)alloc((size_t)N_PAD * F_HID / 2 * 4);    // bf16 (dis-scaled)
    unsigned int* h_bb   = (unsigned int*)alloc((size_t)N_NODES * F_HID / 2 * 4);  // bf16 (dis-scaled)
    unsigned int* agg2b  = (unsigned int*)alloc((size_t)N_NODES * F_HID / 2 * 4);  // bf16 (plain)
    unsigned short* W0Tb = (unsigned short*)alloc((size_t)128 * F_IN * 2);
    unsigned short* W1Tb = (unsigned short*)alloc((size_t)128 * F_HID * 2);
    (void)ws_size; (void)in_sizes; (void)n_in; (void)out_size;

    (void)hipMemsetAsync(indeg, 0, zero_bytes, stream);

    count_deg<<<(N_EDGES + 255) / 256, 256, 0, stream>>>(ei, indeg);
    scan_partial<<<SCAN_NBLK, SCAN_B, 0, stream>>>(indeg, blockSums);
    scan_block_sums<<<1, SCAN_B, 0, stream>>>(blockSums);
    scan_final<<<SCAN_NBLK, SCAN_B, 0, stream>>>(indeg, blockSums, offsets, dis);
    build_csr<<<(N_EDGES + 255) / 256, 256, 0, stream>>>(ei, offsets, indeg, csr);
    cvt_bf16<<<(N_NODES * F_IN / 4 + 255) / 256, 256, 0, stream>>>(x, dis, xb, N_NODES * F_IN / 4);
    cvt_wt2<<<((F_IN + F_HID) * 128 + 255) / 256, 256, 0, stream>>>(W0, W0Tb, W1, W1Tb);

    int agg_grid = (N_NODES + 3) / 4;          // 4 nodes (waves) per block
    int mfma_grid = (N_NODES + 63) / 64;       // 782 blocks

    // layer 0 (reordered): axb = bf16(Â x); h_ab = bf16(relu(axb @ W0 + b0))
    aggregate_xb<<<agg_grid, 256, 0, stream>>>((const uint2*)xb, x, offsets, csr, dis, axb);
    gemm_mfma<F_IN, true, false><<<mfma_grid, 256, 0, stream>>>(
        (const unsigned short*)axb, W0Tb, b0, nullptr, h_ab, N_NODES);
    // layer 1: h_tmpb = bf16(dis * (h_ab @ W1)); h_bb = bf16(dis * relu(Â.. + b1))
    gemm_mfma<F_HID, false, true><<<mfma_grid, 256, 0, stream>>>(
        (const unsigned short*)h_ab, W1Tb, nullptr, dis, h_tmpb, N_NODES);
    aggregate128b<true, true, true><<<agg_grid, 256, 0, stream>>>(
        (const uint2*)h_tmpb, offsets, csr, dis, b1, h_bb);
    // layer 2 (commuted): agg2b = bf16(Â h_bb); pool; then @W2 + b2 in fused head
    aggregate128b<false, false, false><<<agg_grid, 256, 0, stream>>>(
        (const uint2*)h_bb, offsets, csr, dis, nullptr, agg2b);

    // pool + fused (W2 + MLP) head
    pool16<<<(N_NODES + 15) / 16, 128, 0, stream>>>(agg2b, batch, g_acc, g_cnt);
    fused_mlp<<<N_GRAPHS, 512, 0, stream>>>(g_acc, g_cnt, W2, b2, Wm1, bm1, Wm2, bm2,
                                            (float*)d_out);
}